// Round 7
// baseline (1520.783 us; speedup 1.0000x reference)
//
#include <hip/hip_runtime.h>
#include <hip/hip_cooperative_groups.h>
#include <math.h>

// GraphWaveNet forward, MI355X. Round 7: ONE persistent cooperative kernel.
// Phases: [adp_stats | start | repack] -> adpT -> 8x( tcn_mix -> diff 64x128 )
//         -> skip MFMA -> end1 MFMA -> end2, separated by grid.sync().
// Rationale: all kernels <41us; ~26 serialized graph dispatch gaps dominated.
// Diff tile = 64x128 (R5/R6 A/B: occupancy beats barrier amortization here).

namespace cg = cooperative_groups;

#define NBATCH 16
#define LLEN 13
#define NNODE 1024

typedef __attribute__((ext_vector_type(8))) short bf16x8;
typedef __attribute__((ext_vector_type(4))) float f32x4;

#define GLOAD16(gp, lp) __builtin_amdgcn_global_load_lds( \
    (const __attribute__((address_space(1))) void*)(gp), \
    (__attribute__((address_space(3))) void*)(lp), 16, 0, 0)

static __device__ inline short f2bf(float x) {
    union { float f; unsigned u; } v; v.f = x;
    unsigned r = v.u + 0x7FFFu + ((v.u >> 16) & 1u);
    return (short)(r >> 16);
}
static __device__ inline float bf2f(short x) {
    union { unsigned u; float f; } v; v.u = ((unsigned)(unsigned short)x) << 16;
    return v.f;
}

struct P {
    const float *x, *emb, *start_w, *start_b, *tcn_w, *tcn_b, *skip_w, *skip_b;
    const float *gcn_w, *gcn_b, *bn_g, *bn_b, *bn_m, *bn_v, *e1w, *e1b, *e2w, *e2b;
    float* out;
    short* adpT; float* mx; float* inv; float* h; short* gm; short* g12;
    short* wcat; float* sbcat; short* e1wb; short* skipT; short* y1;
};

// 64x128 (MxN) MFMA tile, BK=64, 4 waves as 2x2 (wave tile 32x64), xor-swizzle.
template <int KLEN>
static __device__ __forceinline__ void mfma_tile(
        const short* __restrict__ Abase, int strideA,
        const short* __restrict__ Bbase, int strideB,
        short* As, short* Bs, int tid, f32x4 acc[2][4]) {
    int wave = tid >> 6, lane = tid & 63;
    const short* srcA[2]; short* dstA[2];
    const short* srcB[4]; short* dstB[4];
#pragma unroll
    for (int j = 0; j < 2; ++j) {
        int slot = j * 256 + wave * 64 + lane;
        int row = slot >> 3, pp = slot & 7;
        int col = (pp ^ ((row >> 1) & 7)) * 8;
        srcA[j] = Abase + (size_t)row * strideA + col;
        dstA[j] = As + slot * 8;
    }
#pragma unroll
    for (int j = 0; j < 4; ++j) {
        int slot = j * 256 + wave * 64 + lane;
        int row = slot >> 3, pp = slot & 7;
        int col = (pp ^ ((row >> 1) & 7)) * 8;
        srcB[j] = Bbase + (size_t)row * strideB + col;
        dstB[j] = Bs + slot * 8;
    }
    int wm = (wave & 1) * 32, wn = (wave >> 1) * 64;
    int quad = lane >> 4, lrow = lane & 15;
    const short* paw = As + (wm + lrow) * 64;
    const short* pbw = Bs + (wn + lrow) * 64;
    int off0 = ((quad) ^ ((lrow >> 1) & 7)) * 8;
    int off1 = ((4 + quad) ^ ((lrow >> 1) & 7)) * 8;
#pragma unroll 1
    for (int kk = 0; kk < KLEN; kk += 64) {
#pragma unroll
        for (int j = 0; j < 2; ++j) GLOAD16(srcA[j] + kk, dstA[j]);
#pragma unroll
        for (int j = 0; j < 4; ++j) GLOAD16(srcB[j] + kk, dstB[j]);
        __syncthreads();
#pragma unroll
        for (int ks = 0; ks < 2; ++ks) {
            int off = ks ? off1 : off0;
            bf16x8 a[2], b[4];
#pragma unroll
            for (int i = 0; i < 2; ++i) a[i] = *(const bf16x8*)(paw + i * 16 * 64 + off);
#pragma unroll
            for (int i = 0; i < 4; ++i) b[i] = *(const bf16x8*)(pbw + i * 16 * 64 + off);
#pragma unroll
            for (int mi = 0; mi < 2; ++mi)
#pragma unroll
                for (int ni = 0; ni < 4; ++ni)
                    acc[mi][ni] = __builtin_amdgcn_mfma_f32_16x16x32_bf16(a[mi], b[ni], acc[mi][ni], 0, 0, 0);
        }
        __syncthreads();
    }
}

__global__ __launch_bounds__(256, 2) void gwnet_fused(P p) {
    cg::grid_group grid = cg::this_grid();
    __shared__ __align__(16) char smem[49152];
    short* As = (short*)smem;              // 64x64 shorts  (8 KB)
    short* Bs = (short*)(smem + 8192);     // 128x64 shorts (16 KB)
    int tid = threadIdx.x, bid = blockIdx.x;
    int nb = gridDim.x;
    int nthr = nb * 256;
    int gtid = bid * 256 + tid;
    int lane = tid & 63;

    // ---------- Phase A: adp stats (wave per v) + start conv + repack -------
    {
        int gw = gtid >> 6, nw = nthr >> 6;
        for (int v = gw; v < 1024; v += nw) {
            float ev[10];
#pragma unroll
            for (int k = 0; k < 10; ++k) ev[k] = p.emb[v * 10 + k];
            float m = 0.f, sum = 0.f;
            float sc[16];
#pragma unroll
            for (int j = 0; j < 16; ++j) {
                int w = j * 64 + lane;
                float s = 0.f;
#pragma unroll
                for (int k = 0; k < 10; ++k) s += ev[k] * p.emb[w * 10 + k];
                sc[j] = fmaxf(s, 0.f);
                m = fmaxf(m, sc[j]);
            }
#pragma unroll
            for (int off = 32; off > 0; off >>= 1) m = fmaxf(m, __shfl_xor(m, off));
#pragma unroll
            for (int j = 0; j < 16; ++j) sum += __expf(sc[j] - m);
#pragma unroll
            for (int off = 32; off > 0; off >>= 1) sum += __shfl_xor(sum, off);
            if (lane == 0) { p.mx[v] = m; p.inv[v] = 1.f / sum; }
        }
    }
    for (int it = gtid; it < 16 * 13 * 1024; it += nthr) {
        int n = it & 1023, rest = it >> 10;
        int t = rest % 13, b = rest / 13;
        float2 xv = *(const float2*)(p.x + (size_t)it * 2);
#pragma unroll
        for (int r = 0; r < 32; ++r)
            p.h[((b * 32 + r) * 13 + t) * 1024 + n] =
                p.start_w[r * 2] * xv.x + p.start_w[r * 2 + 1] * xv.y + p.start_b[r];
    }
    for (int idx = gtid; idx < 196608; idx += nthr) {
        if (idx < 65536) {
            int s = idx >> 8, k = idx & 255, i = k >> 5, c = k & 31;
            p.wcat[idx] = f2bf(p.skip_w[(i * 256 + s) * 32 + c]);
        } else {
            int j = idx - 65536;
            p.e1wb[j] = f2bf(p.e1w[j]);
        }
    }
    for (int s = gtid; s < 256; s += nthr) {
        float acc = 0.f;
#pragma unroll
        for (int i = 0; i < 8; ++i) acc += p.skip_b[i * 256 + s];
        p.sbcat[s] = acc;
    }
    grid.sync();

    // ---------- Phase B: adpT[w][v] bf16 ------------------------------------
    for (int idx = gtid; idx < 1024 * 1024; idx += nthr) {
        int w = idx >> 10, v = idx & 1023;
        float s = 0.f;
#pragma unroll
        for (int k = 0; k < 10; ++k) s += p.emb[w * 10 + k] * p.emb[v * 10 + k];
        s = fmaxf(s, 0.f);
        p.adpT[idx] = f2bf(__expf(s - p.mx[v]) * p.inv[v]);
    }
    grid.sync();

    // ---------- Layer loop --------------------------------------------------
    const int dil[8] = {1, 2, 1, 2, 1, 2, 1, 2};
    const int t0s[8] = {1, 3, 4, 6, 7, 9, 10, 12};
#pragma unroll 1
    for (int li = 0; li < 8; ++li) {
        int d = dil[li], t0 = t0s[li], Lt = 13 - t0;
        const float* wt = p.tcn_w + li * 2048;
        const float* bias = p.tcn_b + li * 32;
        const float* gcnw = p.gcn_w + li * 1024;
        // tcn + gating + channel mix
        for (int it = gtid; it < 16 * Lt * 1024; it += nthr) {
            int n = it & 1023, rest = it >> 10;
            int tt = rest % Lt, b = rest / Lt;
            int t = t0 + tt;
            const float* hb = p.h + (((size_t)(b * 32 * 13 + t)) << 10) + n;
            float hp[32], hc[32];
#pragma unroll
            for (int c = 0; c < 32; ++c) {
                hp[c] = hb[(c * 13 - d) * 1024];
                hc[c] = hb[(c * 13) * 1024];
            }
            float gv[32];
#pragma unroll 2
            for (int o = 0; o < 32; ++o) {
                float a0 = bias[o], a1 = 0.f;
#pragma unroll
                for (int c = 0; c < 32; ++c) {
                    a0 += wt[(o * 32 + c) * 2] * hp[c];
                    a1 += wt[(o * 32 + c) * 2 + 1] * hc[c];
                }
                float a = fminf(fmaxf(a0 + a1, -25.f), 25.f);
                float e = __expf(-a), e2 = e * e;
                gv[o] = (1.f - e2) / ((1.f + e2) * (1.f + e));  // tanh*sigmoid
            }
            if (tt == Lt - 1) {  // t == 12
                short* gp = p.g12 + (((size_t)(b << 10) + n) << 8) + li * 32;
#pragma unroll
                for (int c = 0; c < 32; ++c) gp[c] = f2bf(gv[c]);
            }
#pragma unroll 2
            for (int o = 0; o < 32; ++o) {
                float a = 0.f;
#pragma unroll
                for (int c = 0; c < 32; ++c) a += gcnw[o * 32 + c] * gv[c];
                p.gm[(((size_t)((b * 32 + o) * Lt + tt)) << 10) + n] = f2bf(a);
            }
        }
        grid.sync();
        // diffusion MFMA + fused gcn epilogue (bias, relu, residual, BN)
        int tiles = 64 * Lt;  // (8*Lt m-tiles) x (8 n-tiles)
        for (int tile = bid; tile < tiles; tile += nb) {
            int nt = tile & 7, mt = tile >> 3;
            int n0 = nt * 128, m0 = mt * 64;
            f32x4 acc[2][4] = {};
            mfma_tile<1024>(p.gm + ((size_t)m0 << 10), 1024,
                            p.adpT + ((size_t)n0 << 10), 1024, As, Bs, tid, acc);
            int wave = tid >> 6;
            int wm = (wave & 1) * 32, wn = (wave >> 1) * 64;
            int quad = lane >> 4, lrow = lane & 15;
#pragma unroll
            for (int mi = 0; mi < 2; ++mi) {
#pragma unroll
                for (int r = 0; r < 4; ++r) {
                    int m = m0 + wm + mi * 16 + quad * 4 + r;
                    unsigned bc = (unsigned)m / (unsigned)Lt;
                    int tt = m - (int)bc * Lt;
                    int c = bc & 31;
                    float invv = p.bn_g[li * 32 + c] * rsqrtf(p.bn_v[li * 32 + c] + 1e-5f);
                    float meanv = p.bn_m[li * 32 + c];
                    float betav = p.bn_b[li * 32 + c];
                    float gbv = p.gcn_b[li * 32 + c];
                    float* crow = p.h + (((size_t)(bc * 13 + t0 + tt)) << 10) + n0 + wn + lrow;
#pragma unroll
                    for (int ni = 0; ni < 4; ++ni) {
                        float v = fmaxf(acc[mi][ni][r] + gbv, 0.f) + crow[ni * 16];
                        crow[ni * 16] = (v - meanv) * invv + betav;
                    }
                }
            }
        }
        grid.sync();
    }

    // ---------- skip GEMM: skipT[b][n][s] = relu(Wcat @ g12 + sbcat) --------
    for (int tile = bid; tile < 512; tile += nb) {
        int st = tile & 1, mt = (tile >> 1) & 15, b = tile >> 5;
        int s0 = st * 128, m0 = mt * 64;
        f32x4 acc[2][4] = {};
        mfma_tile<256>(p.g12 + (((size_t)((b << 10) + m0)) << 8), 256,
                       p.wcat + ((size_t)s0 << 8), 256, As, Bs, tid, acc);
        int wave = tid >> 6;
        int wm = (wave & 1) * 32, wn = (wave >> 1) * 64;
        int quad = lane >> 4, lrow = lane & 15;
#pragma unroll
        for (int mi = 0; mi < 2; ++mi) {
#pragma unroll
            for (int r = 0; r < 4; ++r) {
                int m = m0 + wm + mi * 16 + quad * 4 + r;  // node n
                short* crow = p.skipT + (((size_t)((b << 10) + m)) << 8) + s0 + wn + lrow;
#pragma unroll
                for (int ni = 0; ni < 4; ++ni) {
                    int col = s0 + wn + lrow + ni * 16;
                    crow[ni * 16] = f2bf(fmaxf(acc[mi][ni][r] + p.sbcat[col], 0.f));
                }
            }
        }
    }
    grid.sync();

    // ---------- end1: y1[b][e][n] = relu(e1w @ skipT + e1b) -----------------
    for (int tile = bid; tile < 1024; tile += nb) {
        int nt = tile & 7, et = (tile >> 3) & 7, b = tile >> 6;
        int n0 = nt * 128, e0 = et * 64;
        f32x4 acc[2][4] = {};
        mfma_tile<256>(p.e1wb + ((size_t)e0 << 8), 256,
                       p.skipT + (((size_t)((b << 10) + n0)) << 8), 256, As, Bs, tid, acc);
        int wave = tid >> 6;
        int wm = (wave & 1) * 32, wn = (wave >> 1) * 64;
        int quad = lane >> 4, lrow = lane & 15;
#pragma unroll
        for (int mi = 0; mi < 2; ++mi) {
#pragma unroll
            for (int r = 0; r < 4; ++r) {
                int e = e0 + wm + mi * 16 + quad * 4 + r;
                float bv = p.e1b[e];
                short* crow = p.y1 + (((size_t)(b * 512 + e)) << 10) + n0 + wn + lrow;
#pragma unroll
                for (int ni = 0; ni < 4; ++ni)
                    crow[ni * 16] = f2bf(fmaxf(acc[mi][ni][r] + bv, 0.f));
            }
        }
    }
    grid.sync();

    // ---------- end2: out[b,n,o] = W2 @ y1 + b2 -----------------------------
    {
        float* sw = (float*)smem;            // 12x512 (24 KB)
        float* ps = (float*)(smem + 24576);  // 4x12x128 (24 KB)
        for (int idx = tid; idx < 6144; idx += 256) sw[idx] = p.e2w[idx];
        __syncthreads();
        for (int wb = bid; wb < 128; wb += nb) {
            int n0 = (wb & 7) * 128, b = wb >> 3;
            int nl = (tid & 63) * 2;
            int ec = tid >> 6;
            float acc0[12], acc1[12];
#pragma unroll
            for (int o = 0; o < 12; ++o) { acc0[o] = 0.f; acc1[o] = 0.f; }
            const short* yb = p.y1 + (((size_t)(b * 512 + ec * 128)) << 10) + n0 + nl;
            for (int e = 0; e < 128; ++e) {
                ushort2 yv = *(const ushort2*)(yb + ((size_t)e << 10));
                float v0 = bf2f((short)yv.x), v1 = bf2f((short)yv.y);
                const float* we = sw + ec * 128 + e;
#pragma unroll
                for (int o = 0; o < 12; ++o) {
                    float wv = we[o * 512];
                    acc0[o] += wv * v0;
                    acc1[o] += wv * v1;
                }
            }
#pragma unroll
            for (int o = 0; o < 12; ++o) {
                ps[(ec * 12 + o) * 128 + nl] = acc0[o];
                ps[(ec * 12 + o) * 128 + nl + 1] = acc1[o];
            }
            __syncthreads();
            for (int idx = tid; idx < 1536; idx += 256) {
                int o = idx >> 7, nn = idx & 127;
                float s = p.e2b[o] + ps[(0 * 12 + o) * 128 + nn] + ps[(1 * 12 + o) * 128 + nn]
                        + ps[(2 * 12 + o) * 128 + nn] + ps[(3 * 12 + o) * 128 + nn];
                p.out[((size_t)((b << 10) + n0 + nn)) * 12 + o] = s;
            }
            __syncthreads();
        }
    }
}

extern "C" void kernel_launch(void* const* d_in, const int* in_sizes, int n_in,
                              void* d_out, int out_size, void* d_ws, size_t ws_size,
                              hipStream_t stream) {
    char* wsb = (char*)d_ws;
    P p;
    p.x       = (const float*)d_in[0];
    p.emb     = (const float*)d_in[1];
    p.start_w = (const float*)d_in[2];
    p.start_b = (const float*)d_in[3];
    p.tcn_w   = (const float*)d_in[4];
    p.tcn_b   = (const float*)d_in[5];
    p.skip_w  = (const float*)d_in[6];
    p.skip_b  = (const float*)d_in[7];
    p.gcn_w   = (const float*)d_in[8];
    p.gcn_b   = (const float*)d_in[9];
    p.bn_g    = (const float*)d_in[10];
    p.bn_b    = (const float*)d_in[11];
    p.bn_m    = (const float*)d_in[12];
    p.bn_v    = (const float*)d_in[13];
    p.e1w     = (const float*)d_in[14];
    p.e1b     = (const float*)d_in[15];
    p.e2w     = (const float*)d_in[16];
    p.e2b     = (const float*)d_in[17];
    p.out     = (float*)d_out;
    p.adpT  = (short*)(wsb);                    // 2,097,152
    p.mx    = (float*)(wsb + 2097152u);         // 4,096
    p.inv   = (float*)(wsb + 2101248u);         // 4,096
    p.h     = (float*)(wsb + 2105344u);         // 27,262,976
    p.gm    = (short*)(wsb + 29368320u);        // 12,582,912 (max Lt=12)
    p.g12   = (short*)(wsb + 41951232u);        // 8,388,608
    p.wcat  = (short*)(wsb + 50339840u);        // 131,072
    p.sbcat = (float*)(wsb + 50470912u);        // 1,024
    p.e1wb  = (short*)(wsb + 50471936u);        // 262,144
    p.skipT = (short*)(wsb + 50734080u);        // 8,388,608
    p.y1    = (short*)(wsb + 59122688u);        // 16,777,216

    int occ = 0;
    hipError_t err = hipOccupancyMaxActiveBlocksPerMultiprocessor(&occ, gwnet_fused, 256, 0);
    if (err != hipSuccess || occ < 1) occ = 2;
    if (occ > 4) occ = 4;
    int nblocks = occ * 256;   // 256 CUs on MI355X

    void* args[] = { (void*)&p };
    hipLaunchCooperativeKernel((const void*)gwnet_fused, dim3(nblocks), dim3(256),
                               args, 0, stream);
}

// Round 8
// 550.996 us; speedup vs baseline: 2.7601x; 2.7601x over previous
//
#include <hip/hip_runtime.h>
#include <math.h>

// GraphWaveNet forward, MI355X. Round 8: revert to R5 multi-kernel structure
// (R7 cooperative grid.sync cost ~45us each on 8 XCDs -> 2.8x regression).
//  - prep kernel merges adp_stats + start conv + weight repack (block ranges)
//  - diff = 64x128/BK=64 xor-swizzled MFMA everywhere (R5/R6 A/B winner)
//  - skip/end1 moved to 64x128 tile (2x blocks vs 128x128)
// Layouts:
//   h    : [B=16, C=32, t=13, N=1024] fp32 (residual stream, in place)
//   gm   : [m=bc*Lt+tt][N] bf16 ; g12 : [b][n][256] bf16 ; adpT : [w][v] bf16
//   skipT: [b][n][s=256] bf16 ; y1 : [b][e=512][n] bf16 ; out [B,N,O] fp32

#define NBATCH 16
#define LLEN 13
#define NNODE 1024

typedef __attribute__((ext_vector_type(8))) short bf16x8;
typedef __attribute__((ext_vector_type(4))) float f32x4;

#define GLOAD16(gp, lp) __builtin_amdgcn_global_load_lds( \
    (const __attribute__((address_space(1))) void*)(gp), \
    (__attribute__((address_space(3))) void*)(lp), 16, 0, 0)

static __device__ inline short f2bf(float x) {
    union { float f; unsigned u; } v; v.f = x;
    unsigned r = v.u + 0x7FFFu + ((v.u >> 16) & 1u);
    return (short)(r >> 16);
}
static __device__ inline float bf2f(short x) {
    union { unsigned u; float f; } v; v.u = ((unsigned)(unsigned short)x) << 16;
    return v.f;
}

// ---------------- prep: adp stats | start conv | weight repack ---------------
// blocks [0,1024): stats; [1024,1856): start; [1856,2624): repack.
__global__ __launch_bounds__(256) void prep_kernel(
        const float* __restrict__ emb, const float* __restrict__ x,
        const float* __restrict__ start_w, const float* __restrict__ start_b,
        const float* __restrict__ skip_w, const float* __restrict__ skip_b,
        const float* __restrict__ e1w,
        float* __restrict__ mx, float* __restrict__ inv, float* __restrict__ h,
        short* __restrict__ wcat, float* __restrict__ sbcat, short* __restrict__ e1wb) {
    int bid = blockIdx.x;
    int tid = threadIdx.x;
    if (bid < 1024) {
        int v = bid;
        __shared__ float red[256];
        float ev[10];
#pragma unroll
        for (int k = 0; k < 10; ++k) ev[k] = emb[v * 10 + k];
        float sc[4];
#pragma unroll
        for (int j = 0; j < 4; ++j) {
            int w = tid + j * 256;
            float s = 0.f;
#pragma unroll
            for (int k = 0; k < 10; ++k) s += ev[k] * emb[w * 10 + k];
            sc[j] = fmaxf(s, 0.f);
        }
        float m = fmaxf(fmaxf(sc[0], sc[1]), fmaxf(sc[2], sc[3]));
        red[tid] = m;
        __syncthreads();
        for (int s = 128; s > 0; s >>= 1) {
            if (tid < s) red[tid] = fmaxf(red[tid], red[tid + s]);
            __syncthreads();
        }
        m = red[0];
        __syncthreads();
        float sum = 0.f;
#pragma unroll
        for (int j = 0; j < 4; ++j) sum += __expf(sc[j] - m);
        red[tid] = sum;
        __syncthreads();
        for (int s = 128; s > 0; s >>= 1) {
            if (tid < s) red[tid] += red[tid + s];
            __syncthreads();
        }
        if (tid == 0) { mx[v] = m; inv[v] = 1.f / red[0]; }
    } else if (bid < 1856) {
        int it = (bid - 1024) * 256 + tid;   // < 212992
        int n = it & 1023, rest = it >> 10;
        int t = rest % 13, b = rest / 13;
        float2 xv = *(const float2*)(x + (size_t)it * 2);
#pragma unroll
        for (int r = 0; r < 32; ++r)
            h[((b * 32 + r) * 13 + t) * 1024 + n] =
                start_w[r * 2] * xv.x + start_w[r * 2 + 1] * xv.y + start_b[r];
    } else {
        int idx = (bid - 1856) * 256 + tid;  // < 196608
        if (idx < 65536) {
            int s = idx >> 8, k = idx & 255, i = k >> 5, c = k & 31;
            wcat[idx] = f2bf(skip_w[(i * 256 + s) * 32 + c]);
        } else {
            int j = idx - 65536;
            e1wb[j] = f2bf(e1w[j]);
        }
        if (idx < 256) {
            float s = 0.f;
#pragma unroll
            for (int i = 0; i < 8; ++i) s += skip_b[i * 256 + idx];
            sbcat[idx] = s;
        }
    }
}

// ---------------- adpT[w][v] = softmax_v(relu(E E^T))[v][w] bf16 ------------
__global__ void adpT_kernel(const float* __restrict__ emb, const float* __restrict__ mx,
                            const float* __restrict__ inv, short* __restrict__ adpT) {
    int w = blockIdx.x;
    int tid = threadIdx.x;
    __shared__ float ew[10];
    if (tid < 10) ew[tid] = emb[w * 10 + tid];
    __syncthreads();
#pragma unroll
    for (int j = 0; j < 4; ++j) {
        int v = tid + j * 256;
        float s = 0.f;
#pragma unroll
        for (int k = 0; k < 10; ++k) s += ew[k] * emb[v * 10 + k];
        s = fmaxf(s, 0.f);
        adpT[w * 1024 + v] = f2bf(__expf(s - mx[v]) * inv[v]);
    }
}

// ---------------- TCN conv + gating + gcn channel-mix -> gm bf16 -------------
// Weights read with wave-uniform indices -> scalar loads (SGPR), no LDS.
__global__ __launch_bounds__(128) void tcn_mix_kernel(
        const float* __restrict__ h, short* __restrict__ gm,
        short* __restrict__ g12,
        const float* __restrict__ w, const float* __restrict__ bias,
        const float* __restrict__ gcnw,
        int d, int t0, int Lt, int li) {
    int tid = threadIdx.x;
    int n = blockIdx.x * 128 + tid;
    int tt = blockIdx.y;
    int t = t0 + tt;
    int bb = blockIdx.z;
    const float* hb = h + (((size_t)(bb * 32 * LLEN + t)) << 10) + n;
    float hp[32], hc[32];
#pragma unroll
    for (int c = 0; c < 32; ++c) {
        hp[c] = hb[(c * LLEN - d) * 1024];
        hc[c] = hb[(c * LLEN) * 1024];
    }
    float gv[32];
#pragma unroll 2
    for (int o = 0; o < 32; ++o) {
        float a0 = bias[o], a1 = 0.f;
#pragma unroll
        for (int c = 0; c < 32; ++c) {
            a0 += w[(o * 32 + c) * 2] * hp[c];
            a1 += w[(o * 32 + c) * 2 + 1] * hc[c];
        }
        float a = fminf(fmaxf(a0 + a1, -25.f), 25.f);
        float e = __expf(-a);
        float e2 = e * e;
        gv[o] = (1.f - e2) / ((1.f + e2) * (1.f + e));  // tanh(a)*sigmoid(a)
    }
    if (t == 12) {
        short* gp = g12 + (((size_t)(bb << 10) + n) << 8) + li * 32;
#pragma unroll
        for (int c = 0; c < 32; ++c) gp[c] = f2bf(gv[c]);
    }
#pragma unroll 2
    for (int o = 0; o < 32; ++o) {
        float a = 0.f;
#pragma unroll
        for (int c = 0; c < 32; ++c) a += gcnw[o * 32 + c] * gv[c];
        gm[(((size_t)((bb * 32 + o) * Lt + tt)) << 10) + n] = f2bf(a);
    }
}

// ======== shared 64x128 MFMA tile helper (BK=64, xor-swizzled LDS) ==========
template <int KLEN>
static __device__ __forceinline__ void mfma_tile(
        const short* __restrict__ Abase, int strideA,
        const short* __restrict__ Bbase, int strideB,
        short* As, short* Bs, int tid, f32x4 acc[2][4]) {
    int wave = tid >> 6, lane = tid & 63;
    const short* srcA[2]; short* dstA[2];
    const short* srcB[4]; short* dstB[4];
#pragma unroll
    for (int j = 0; j < 2; ++j) {
        int slot = j * 256 + wave * 64 + lane;
        int row = slot >> 3, pp = slot & 7;
        int col = (pp ^ ((row >> 1) & 7)) * 8;
        srcA[j] = Abase + (size_t)row * strideA + col;
        dstA[j] = As + slot * 8;
    }
#pragma unroll
    for (int j = 0; j < 4; ++j) {
        int slot = j * 256 + wave * 64 + lane;
        int row = slot >> 3, pp = slot & 7;
        int col = (pp ^ ((row >> 1) & 7)) * 8;
        srcB[j] = Bbase + (size_t)row * strideB + col;
        dstB[j] = Bs + slot * 8;
    }
    int wm = (wave & 1) * 32, wn = (wave >> 1) * 64;
    int quad = lane >> 4, lrow = lane & 15;
    const short* paw = As + (wm + lrow) * 64;
    const short* pbw = Bs + (wn + lrow) * 64;
    int off0 = ((quad) ^ ((lrow >> 1) & 7)) * 8;
    int off1 = ((4 + quad) ^ ((lrow >> 1) & 7)) * 8;
#pragma unroll 1
    for (int kk = 0; kk < KLEN; kk += 64) {
#pragma unroll
        for (int j = 0; j < 2; ++j) GLOAD16(srcA[j] + kk, dstA[j]);
#pragma unroll
        for (int j = 0; j < 4; ++j) GLOAD16(srcB[j] + kk, dstB[j]);
        __syncthreads();
#pragma unroll
        for (int ks = 0; ks < 2; ++ks) {
            int off = ks ? off1 : off0;
            bf16x8 a[2], b[4];
#pragma unroll
            for (int i = 0; i < 2; ++i) a[i] = *(const bf16x8*)(paw + i * 16 * 64 + off);
#pragma unroll
            for (int i = 0; i < 4; ++i) b[i] = *(const bf16x8*)(pbw + i * 16 * 64 + off);
#pragma unroll
            for (int mi = 0; mi < 2; ++mi)
#pragma unroll
                for (int ni = 0; ni < 4; ++ni)
                    acc[mi][ni] = __builtin_amdgcn_mfma_f32_16x16x32_bf16(a[mi], b[ni], acc[mi][ni], 0, 0, 0);
        }
        __syncthreads();
    }
}

// ---------------- diffusion MFMA + fused gcn epilogue (64x128) ---------------
__global__ __launch_bounds__(256) void diff_fused(const short* __restrict__ gm,
                                                  const short* __restrict__ adpT,
                                                  float* __restrict__ h,
                                                  const float* __restrict__ gb,
                                                  const float* __restrict__ bng,
                                                  const float* __restrict__ bnb,
                                                  const float* __restrict__ bnm,
                                                  const float* __restrict__ bnv,
                                                  int t0, int Lt) {
    __shared__ __align__(16) short As[64 * 64];
    __shared__ __align__(16) short Bs[128 * 64];
    __shared__ float sgb[32], sinv[32], smean[32], sbeta[32];
    int tid = threadIdx.x;
    int n0 = blockIdx.x * 128;
    int m0 = blockIdx.y * 64;
    if (tid < 32) {
        sgb[tid] = gb[tid];
        sinv[tid] = bng[tid] * rsqrtf(bnv[tid] + 1e-5f);
        smean[tid] = bnm[tid];
        sbeta[tid] = bnb[tid];
    }
    f32x4 acc[2][4] = {};
    mfma_tile<1024>(gm + ((size_t)m0 << 10), 1024,
                    adpT + ((size_t)n0 << 10), 1024, As, Bs, tid, acc);
    int wave = tid >> 6, lane = tid & 63;
    int wm = (wave & 1) * 32, wn = (wave >> 1) * 64;
    int quad = lane >> 4, lrow = lane & 15;
#pragma unroll
    for (int mi = 0; mi < 2; ++mi) {
#pragma unroll
        for (int r = 0; r < 4; ++r) {
            int m = m0 + wm + mi * 16 + quad * 4 + r;
            unsigned bc = (unsigned)m / (unsigned)Lt;
            int tt = m - (int)bc * Lt;
            int c = bc & 31;
            float invv = sinv[c], meanv = smean[c], betav = sbeta[c], gbv = sgb[c];
            float* crow = h + (((size_t)(bc * LLEN + t0 + tt)) << 10) + n0 + wn + lrow;
#pragma unroll
            for (int ni = 0; ni < 4; ++ni) {
                float v = fmaxf(acc[mi][ni][r] + gbv, 0.f) + crow[ni * 16];
                crow[ni * 16] = (v - meanv) * invv + betav;
            }
        }
    }
}

// ---------------- skip GEMM (64x128): skipT = relu(Wcat @ g12 + sbcat) ------
__global__ __launch_bounds__(256) void skip_mfma(const short* __restrict__ g12,
                                                 const short* __restrict__ wcat,
                                                 const float* __restrict__ sbcat,
                                                 short* __restrict__ skipT) {
    __shared__ __align__(16) short As[64 * 64];
    __shared__ __align__(16) short Bs[128 * 64];
    int tid = threadIdx.x;
    int s0 = blockIdx.x * 128;
    int m0 = blockIdx.y * 64;   // n rows
    int b = blockIdx.z;
    f32x4 acc[2][4] = {};
    mfma_tile<256>(g12 + (((size_t)((b << 10) + m0)) << 8), 256,
                   wcat + ((size_t)s0 << 8), 256, As, Bs, tid, acc);
    int wave = tid >> 6, lane = tid & 63;
    int wm = (wave & 1) * 32, wn = (wave >> 1) * 64;
    int quad = lane >> 4, lrow = lane & 15;
#pragma unroll
    for (int mi = 0; mi < 2; ++mi) {
#pragma unroll
        for (int r = 0; r < 4; ++r) {
            int m = m0 + wm + mi * 16 + quad * 4 + r;   // node n
            short* crow = skipT + (((size_t)((b << 10) + m)) << 8) + s0 + wn + lrow;
#pragma unroll
            for (int ni = 0; ni < 4; ++ni) {
                int col = s0 + wn + lrow + ni * 16;
                crow[ni * 16] = f2bf(fmaxf(acc[mi][ni][r] + sbcat[col], 0.f));
            }
        }
    }
}

// ---------------- end1 (64x128): y1 = relu(e1w @ skipT + e1b) ----------------
__global__ __launch_bounds__(256) void end1_mfma(const short* __restrict__ skipT,
                                                 const short* __restrict__ e1wb,
                                                 const float* __restrict__ e1b,
                                                 short* __restrict__ y1) {
    __shared__ __align__(16) short As[64 * 64];
    __shared__ __align__(16) short Bs[128 * 64];
    int tid = threadIdx.x;
    int n0 = blockIdx.x * 128;
    int e0 = blockIdx.y * 64;
    int b = blockIdx.z;
    f32x4 acc[2][4] = {};
    mfma_tile<256>(e1wb + ((size_t)e0 << 8), 256,
                   skipT + (((size_t)((b << 10) + n0)) << 8), 256, As, Bs, tid, acc);
    int wave = tid >> 6, lane = tid & 63;
    int wm = (wave & 1) * 32, wn = (wave >> 1) * 64;
    int quad = lane >> 4, lrow = lane & 15;
#pragma unroll
    for (int mi = 0; mi < 2; ++mi) {
#pragma unroll
        for (int r = 0; r < 4; ++r) {
            int e = e0 + wm + mi * 16 + quad * 4 + r;
            float bv = e1b[e];
            short* crow = y1 + (((size_t)(b * 512 + e)) << 10) + n0 + wn + lrow;
#pragma unroll
            for (int ni = 0; ni < 4; ++ni)
                crow[ni * 16] = f2bf(fmaxf(acc[mi][ni][r] + bv, 0.f));
        }
    }
}

// ---------------- end2: out[b,n,o] = W2 @ y1 + b2 (parallel e-split) --------
__global__ __launch_bounds__(256) void end2_kernel(const short* __restrict__ y1,
                                                   const float* __restrict__ w2,
                                                   const float* __restrict__ b2,
                                                   float* __restrict__ out) {
    __shared__ float sw[12][512];
    __shared__ float ps[4][12][128];
    int tid = threadIdx.x;
    for (int idx = tid; idx < 6144; idx += 256) sw[idx >> 9][idx & 511] = w2[idx];
    __syncthreads();
    int n0 = blockIdx.x * 128;
    int bb = blockIdx.y;
    int nl = (tid & 63) * 2;
    int ec = tid >> 6;
    float acc0[12], acc1[12];
#pragma unroll
    for (int o = 0; o < 12; ++o) { acc0[o] = 0.f; acc1[o] = 0.f; }
    const short* yb = y1 + (((size_t)(bb * 512 + ec * 128)) << 10) + n0 + nl;
    for (int e = 0; e < 128; ++e) {
        ushort2 yv = *(const ushort2*)(yb + ((size_t)e << 10));
        float v0 = bf2f((short)yv.x), v1 = bf2f((short)yv.y);
        const float* we = &sw[0][ec * 128 + e];
#pragma unroll
        for (int o = 0; o < 12; ++o) {
            float wv = we[o * 512];
            acc0[o] += wv * v0;
            acc1[o] += wv * v1;
        }
    }
#pragma unroll
    for (int o = 0; o < 12; ++o) {
        ps[ec][o][nl] = acc0[o];
        ps[ec][o][nl + 1] = acc1[o];
    }
    __syncthreads();
    for (int idx = tid; idx < 1536; idx += 256) {
        int o = idx >> 7, nn = idx & 127;
        float s = b2[o] + ps[0][o][nn] + ps[1][o][nn] + ps[2][o][nn] + ps[3][o][nn];
        out[((size_t)(bb * NNODE + n0 + nn)) * 12 + o] = s;
    }
}

extern "C" void kernel_launch(void* const* d_in, const int* in_sizes, int n_in,
                              void* d_out, int out_size, void* d_ws, size_t ws_size,
                              hipStream_t stream) {
    const float* x       = (const float*)d_in[0];
    const float* emb     = (const float*)d_in[1];
    const float* start_w = (const float*)d_in[2];
    const float* start_b = (const float*)d_in[3];
    const float* tcn_w   = (const float*)d_in[4];
    const float* tcn_b   = (const float*)d_in[5];
    const float* skip_w  = (const float*)d_in[6];
    const float* skip_b  = (const float*)d_in[7];
    const float* gcn_w   = (const float*)d_in[8];
    const float* gcn_b   = (const float*)d_in[9];
    const float* bn_g    = (const float*)d_in[10];
    const float* bn_b    = (const float*)d_in[11];
    const float* bn_m    = (const float*)d_in[12];
    const float* bn_v    = (const float*)d_in[13];
    const float* e1w     = (const float*)d_in[14];
    const float* e1b     = (const float*)d_in[15];
    const float* e2w     = (const float*)d_in[16];
    const float* e2b     = (const float*)d_in[17];
    float* out = (float*)d_out;

    char* wsb = (char*)d_ws;
    short* adpT  = (short*)(wsb);                    // 2,097,152
    float* mx    = (float*)(wsb + 2097152u);         // 4,096
    float* inv   = (float*)(wsb + 2101248u);         // 4,096
    float* h     = (float*)(wsb + 2105344u);         // 27,262,976
    short* gm    = (short*)(wsb + 29368320u);        // 12,582,912 (max Lt=12)
    short* g12   = (short*)(wsb + 41951232u);        // 8,388,608
    short* wcat  = (short*)(wsb + 50339840u);        // 131,072
    float* sbcat = (float*)(wsb + 50470912u);        // 1,024
    short* e1wb  = (short*)(wsb + 50471936u);        // 262,144
    short* skipT = (short*)(wsb + 50734080u);        // 8,388,608
    short* y1    = (short*)(wsb + 59122688u);        // 16,777,216

    prep_kernel<<<dim3(2624), dim3(256), 0, stream>>>(
        emb, x, start_w, start_b, skip_w, skip_b, e1w,
        mx, inv, h, wcat, sbcat, e1wb);
    adpT_kernel<<<dim3(1024), dim3(256), 0, stream>>>(emb, mx, inv, adpT);

    const int dil[8] = {1, 2, 1, 2, 1, 2, 1, 2};
    const int t0s[8] = {1, 3, 4, 6, 7, 9, 10, 12};
    for (int i = 0; i < 8; ++i) {
        int d = dil[i];
        int t0 = t0s[i];
        int Lt = 13 - t0;
        tcn_mix_kernel<<<dim3(8, Lt, 16), dim3(128), 0, stream>>>(
            h, gm, g12, tcn_w + i * 2048, tcn_b + i * 32, gcn_w + i * 1024,
            d, t0, Lt, i);
        diff_fused<<<dim3(8, 8 * Lt), dim3(256), 0, stream>>>(
            gm, adpT, h, gcn_b + i * 32,
            bn_g + i * 32, bn_b + i * 32, bn_m + i * 32, bn_v + i * 32, t0, Lt);
    }

    skip_mfma<<<dim3(2, 16, 16), dim3(256), 0, stream>>>(g12, wcat, sbcat, skipT);
    end1_mfma<<<dim3(8, 8, 16), dim3(256), 0, stream>>>(skipT, e1wb, e1b, y1);
    end2_kernel<<<dim3(8, 16), dim3(256), 0, stream>>>(y1, e2w, e2b, out);
}

// Round 9
// 392.923 us; speedup vs baseline: 3.8704x; 1.4023x over previous
//
#include <hip/hip_runtime.h>
#include <math.h>

// GraphWaveNet forward, MI355X. Round 9: tcn rewritten as MFMA (32x32x16).
// Cross-round decomposition showed tcn_mix ~40us/dispatch (~58% of total),
// latency-bound on dependent FMA chains + weight fetches. tcn is GEMM-shaped:
//   conv = [W0|W1](32x64) @ [h(t-d);h(t)](64xN); gate elementwise in C/D regs;
//   gm = Gw(32x32) @ gv via half-wave reg relayout (shfl_xor 32).
// Everything else = R8 structure (diff 64x128/BK64 swizzled, prep merged).

#define NBATCH 16
#define LLEN 13
#define NNODE 1024

typedef __attribute__((ext_vector_type(8))) short bf16x8;
typedef __attribute__((ext_vector_type(4))) float f32x4;
typedef __attribute__((ext_vector_type(16))) float f32x16;

#define GLOAD16(gp, lp) __builtin_amdgcn_global_load_lds( \
    (const __attribute__((address_space(1))) void*)(gp), \
    (__attribute__((address_space(3))) void*)(lp), 16, 0, 0)

static __device__ inline short f2bf(float x) {
    union { float f; unsigned u; } v; v.f = x;
    unsigned r = v.u + 0x7FFFu + ((v.u >> 16) & 1u);
    return (short)(r >> 16);
}
static __device__ inline float bf2f(short x) {
    union { unsigned u; float f; } v; v.u = ((unsigned)(unsigned short)x) << 16;
    return v.f;
}
static __device__ inline unsigned pack2bf(float lo, float hi) {
    return (unsigned)(unsigned short)f2bf(lo) | ((unsigned)(unsigned short)f2bf(hi) << 16);
}

// ---------------- prep: adp stats | start conv | weight repack ---------------
__global__ __launch_bounds__(256) void prep_kernel(
        const float* __restrict__ emb, const float* __restrict__ x,
        const float* __restrict__ start_w, const float* __restrict__ start_b,
        const float* __restrict__ skip_w, const float* __restrict__ skip_b,
        const float* __restrict__ e1w,
        float* __restrict__ mx, float* __restrict__ inv, float* __restrict__ h,
        short* __restrict__ wcat, float* __restrict__ sbcat, short* __restrict__ e1wb) {
    int bid = blockIdx.x;
    int tid = threadIdx.x;
    if (bid < 1024) {
        int v = bid;
        __shared__ float red[256];
        float ev[10];
#pragma unroll
        for (int k = 0; k < 10; ++k) ev[k] = emb[v * 10 + k];
        float sc[4];
#pragma unroll
        for (int j = 0; j < 4; ++j) {
            int w = tid + j * 256;
            float s = 0.f;
#pragma unroll
            for (int k = 0; k < 10; ++k) s += ev[k] * emb[w * 10 + k];
            sc[j] = fmaxf(s, 0.f);
        }
        float m = fmaxf(fmaxf(sc[0], sc[1]), fmaxf(sc[2], sc[3]));
        red[tid] = m;
        __syncthreads();
        for (int s = 128; s > 0; s >>= 1) {
            if (tid < s) red[tid] = fmaxf(red[tid], red[tid + s]);
            __syncthreads();
        }
        m = red[0];
        __syncthreads();
        float sum = 0.f;
#pragma unroll
        for (int j = 0; j < 4; ++j) sum += __expf(sc[j] - m);
        red[tid] = sum;
        __syncthreads();
        for (int s = 128; s > 0; s >>= 1) {
            if (tid < s) red[tid] += red[tid + s];
            __syncthreads();
        }
        if (tid == 0) { mx[v] = m; inv[v] = 1.f / red[0]; }
    } else if (bid < 1856) {
        int it = (bid - 1024) * 256 + tid;
        int n = it & 1023, rest = it >> 10;
        int t = rest % 13, b = rest / 13;
        float2 xv = *(const float2*)(x + (size_t)it * 2);
#pragma unroll
        for (int r = 0; r < 32; ++r)
            h[((b * 32 + r) * 13 + t) * 1024 + n] =
                start_w[r * 2] * xv.x + start_w[r * 2 + 1] * xv.y + start_b[r];
    } else {
        int idx = (bid - 1856) * 256 + tid;
        if (idx < 65536) {
            int s = idx >> 8, k = idx & 255, i = k >> 5, c = k & 31;
            wcat[idx] = f2bf(skip_w[(i * 256 + s) * 32 + c]);
        } else {
            int j = idx - 65536;
            e1wb[j] = f2bf(e1w[j]);
        }
        if (idx < 256) {
            float s = 0.f;
#pragma unroll
            for (int i = 0; i < 8; ++i) s += skip_b[i * 256 + idx];
            sbcat[idx] = s;
        }
    }
}

// ---------------- adpT[w][v] = softmax_v(relu(E E^T))[v][w] bf16 ------------
__global__ void adpT_kernel(const float* __restrict__ emb, const float* __restrict__ mx,
                            const float* __restrict__ inv, short* __restrict__ adpT) {
    int w = blockIdx.x;
    int tid = threadIdx.x;
    __shared__ float ew[10];
    if (tid < 10) ew[tid] = emb[w * 10 + tid];
    __syncthreads();
#pragma unroll
    for (int j = 0; j < 4; ++j) {
        int v = tid + j * 256;
        float s = 0.f;
#pragma unroll
        for (int k = 0; k < 10; ++k) s += ew[k] * emb[v * 10 + k];
        s = fmaxf(s, 0.f);
        adpT[w * 1024 + v] = f2bf(__expf(s - mx[v]) * inv[v]);
    }
}

// ---------------- TCN as MFMA: conv+gate+mix -> gm bf16 ----------------------
// Per wave: one (b,t), 32 nodes. conv = [W0|W1] @ [h(t-d);h(t)] (M=32,K=64),
// gate in C/D regs, relayout via shfl_xor(32), mix = Gw @ gv (K=32).
// 32x32x16 layouts: A m=lane&31,k=(lane>>5)*8+j; B n=lane&31,k=(lane>>5)*8+j;
// C/D col=lane&31, row=(r&3)+8*(r>>2)+4*(lane>>5).
__global__ __launch_bounds__(256) void tcn_mfma(
        const float* __restrict__ h, short* __restrict__ gm,
        short* __restrict__ g12,
        const float* __restrict__ w, const float* __restrict__ bias,
        const float* __restrict__ gcnw,
        int d, int t0, int Lt, int li) {
    int tid = threadIdx.x;
    int wave = tid >> 6, lane = tid & 63;
    int m = lane & 31, hw = lane >> 5;
    int tt = blockIdx.y, t = t0 + tt, b = blockIdx.z;
    int n = blockIdx.x * 128 + wave * 32 + m;

    // A frags: [W0|W1] 32x64 bf16
    bf16x8 afrag[4];
#pragma unroll
    for (int q = 0; q < 4; ++q) {
        int kbase = q * 16 + hw * 8;
        float tmp[8];
#pragma unroll
        for (int j = 0; j < 8; ++j) {
            int k = kbase + j;
            int tap = k >> 5, c = k & 31;
            tmp[j] = w[(m * 32 + c) * 2 + tap];
        }
        bf16x8 fr;
#pragma unroll
        for (int j = 0; j < 8; ++j) fr[j] = f2bf(tmp[j]);
        afrag[q] = fr;
    }
    // B frags: stacked h taps (rows k<32: h[t-d][c=k]; k>=32: h[t][c=k-32])
    bf16x8 bfrag[4];
#pragma unroll
    for (int q = 0; q < 4; ++q) {
        int kbase = q * 16 + hw * 8;
        int tap = kbase >> 5, c0 = kbase & 31;
        int tc = tap ? t : (t - d);
        const float* hb = h + (((size_t)((b * 32 + c0) * 13 + tc)) << 10) + n;
        bf16x8 fr;
#pragma unroll
        for (int j = 0; j < 8; ++j) fr[j] = f2bf(hb[(size_t)j * 13 * 1024]);
        bfrag[q] = fr;
    }
    f32x16 conv = {};
#pragma unroll
    for (int q = 0; q < 4; ++q)
        conv = __builtin_amdgcn_mfma_f32_32x32x16_bf16(afrag[q], bfrag[q], conv, 0, 0, 0);

    // bias + gating (elementwise in C/D regs)
    float gv[16];
#pragma unroll
    for (int r = 0; r < 16; ++r) {
        int o0 = (r & 3) + 8 * (r >> 2);
        float bv = hw ? bias[o0 + 4] : bias[o0];
        float a = conv[r] + bv;
        a = fminf(fmaxf(a, -25.f), 25.f);
        float e = __expf(-a), e2 = e * e;
        gv[r] = (1.f - e2) / ((1.f + e2) * (1.f + e));  // tanh(a)*sigmoid(a)
    }
    if (tt == Lt - 1) {  // t == 12: stash gated output for the skip GEMM
        short* gp = g12 + (((size_t)((b << 10) + n)) << 8) + li * 32;
#pragma unroll
        for (int r = 0; r < 16; ++r) {
            int o = (r & 3) + 8 * (r >> 2) + 4 * hw;
            gp[o] = f2bf(gv[r]);
        }
    }
    // relayout gv (C/D) -> B-operand frags for the mix GEMM
    unsigned pr[8], sp[8];
#pragma unroll
    for (int i = 0; i < 8; ++i) {
        pr[i] = pack2bf(gv[2 * i], gv[2 * i + 1]);
        sp[i] = (unsigned)__shfl_xor((int)pr[i], 32);
    }
    bf16x8 mfrag[2];
#pragma unroll
    for (int q = 0; q < 2; ++q) {
        union { unsigned u[4]; bf16x8 v; } tmpu;
        tmpu.u[0] = hw ? sp[q * 4 + 2] : pr[q * 4 + 0];
        tmpu.u[1] = hw ? sp[q * 4 + 3] : pr[q * 4 + 1];
        tmpu.u[2] = hw ? pr[q * 4 + 2] : sp[q * 4 + 0];
        tmpu.u[3] = hw ? pr[q * 4 + 3] : sp[q * 4 + 1];
        mfrag[q] = tmpu.v;
    }
    // mix A-frags: Gw 32x32
    bf16x8 gwfrag[2];
#pragma unroll
    for (int q = 0; q < 2; ++q) {
        int kbase = q * 16 + hw * 8;
        bf16x8 fr;
#pragma unroll
        for (int j = 0; j < 8; ++j) fr[j] = f2bf(gcnw[m * 32 + kbase + j]);
        gwfrag[q] = fr;
    }
    f32x16 mix = {};
    mix = __builtin_amdgcn_mfma_f32_32x32x16_bf16(gwfrag[0], mfrag[0], mix, 0, 0, 0);
    mix = __builtin_amdgcn_mfma_f32_32x32x16_bf16(gwfrag[1], mfrag[1], mix, 0, 0, 0);
#pragma unroll
    for (int r = 0; r < 16; ++r) {
        int o2 = (r & 3) + 8 * (r >> 2) + 4 * hw;
        gm[(((size_t)((b * 32 + o2) * Lt + tt)) << 10) + n] = f2bf(mix[r]);
    }
}

// ======== shared 64x128 MFMA tile helper (BK=64, xor-swizzled LDS) ==========
template <int KLEN>
static __device__ __forceinline__ void mfma_tile(
        const short* __restrict__ Abase, int strideA,
        const short* __restrict__ Bbase, int strideB,
        short* As, short* Bs, int tid, f32x4 acc[2][4]) {
    int wave = tid >> 6, lane = tid & 63;
    const short* srcA[2]; short* dstA[2];
    const short* srcB[4]; short* dstB[4];
#pragma unroll
    for (int j = 0; j < 2; ++j) {
        int slot = j * 256 + wave * 64 + lane;
        int row = slot >> 3, pp = slot & 7;
        int col = (pp ^ ((row >> 1) & 7)) * 8;
        srcA[j] = Abase + (size_t)row * strideA + col;
        dstA[j] = As + slot * 8;
    }
#pragma unroll
    for (int j = 0; j < 4; ++j) {
        int slot = j * 256 + wave * 64 + lane;
        int row = slot >> 3, pp = slot & 7;
        int col = (pp ^ ((row >> 1) & 7)) * 8;
        srcB[j] = Bbase + (size_t)row * strideB + col;
        dstB[j] = Bs + slot * 8;
    }
    int wm = (wave & 1) * 32, wn = (wave >> 1) * 64;
    int quad = lane >> 4, lrow = lane & 15;
    const short* paw = As + (wm + lrow) * 64;
    const short* pbw = Bs + (wn + lrow) * 64;
    int off0 = ((quad) ^ ((lrow >> 1) & 7)) * 8;
    int off1 = ((4 + quad) ^ ((lrow >> 1) & 7)) * 8;
#pragma unroll 1
    for (int kk = 0; kk < KLEN; kk += 64) {
#pragma unroll
        for (int j = 0; j < 2; ++j) GLOAD16(srcA[j] + kk, dstA[j]);
#pragma unroll
        for (int j = 0; j < 4; ++j) GLOAD16(srcB[j] + kk, dstB[j]);
        __syncthreads();
#pragma unroll
        for (int ks = 0; ks < 2; ++ks) {
            int off = ks ? off1 : off0;
            bf16x8 a[2], b[4];
#pragma unroll
            for (int i = 0; i < 2; ++i) a[i] = *(const bf16x8*)(paw + i * 16 * 64 + off);
#pragma unroll
            for (int i = 0; i < 4; ++i) b[i] = *(const bf16x8*)(pbw + i * 16 * 64 + off);
#pragma unroll
            for (int mi = 0; mi < 2; ++mi)
#pragma unroll
                for (int ni = 0; ni < 4; ++ni)
                    acc[mi][ni] = __builtin_amdgcn_mfma_f32_16x16x32_bf16(a[mi], b[ni], acc[mi][ni], 0, 0, 0);
        }
        __syncthreads();
    }
}

// ---------------- diffusion MFMA + fused gcn epilogue (64x128) ---------------
__global__ __launch_bounds__(256) void diff_fused(const short* __restrict__ gm,
                                                  const short* __restrict__ adpT,
                                                  float* __restrict__ h,
                                                  const float* __restrict__ gb,
                                                  const float* __restrict__ bng,
                                                  const float* __restrict__ bnb,
                                                  const float* __restrict__ bnm,
                                                  const float* __restrict__ bnv,
                                                  int t0, int Lt) {
    __shared__ __align__(16) short As[64 * 64];
    __shared__ __align__(16) short Bs[128 * 64];
    __shared__ float sgb[32], sinv[32], smean[32], sbeta[32];
    int tid = threadIdx.x;
    int n0 = blockIdx.x * 128;
    int m0 = blockIdx.y * 64;
    if (tid < 32) {
        sgb[tid] = gb[tid];
        sinv[tid] = bng[tid] * rsqrtf(bnv[tid] + 1e-5f);
        smean[tid] = bnm[tid];
        sbeta[tid] = bnb[tid];
    }
    f32x4 acc[2][4] = {};
    mfma_tile<1024>(gm + ((size_t)m0 << 10), 1024,
                    adpT + ((size_t)n0 << 10), 1024, As, Bs, tid, acc);
    int wave = tid >> 6, lane = tid & 63;
    int wm = (wave & 1) * 32, wn = (wave >> 1) * 64;
    int quad = lane >> 4, lrow = lane & 15;
#pragma unroll
    for (int mi = 0; mi < 2; ++mi) {
#pragma unroll
        for (int r = 0; r < 4; ++r) {
            int m = m0 + wm + mi * 16 + quad * 4 + r;
            unsigned bc = (unsigned)m / (unsigned)Lt;
            int tt = m - (int)bc * Lt;
            int c = bc & 31;
            float invv = sinv[c], meanv = smean[c], betav = sbeta[c], gbv = sgb[c];
            float* crow = h + (((size_t)(bc * LLEN + t0 + tt)) << 10) + n0 + wn + lrow;
#pragma unroll
            for (int ni = 0; ni < 4; ++ni) {
                float v = fmaxf(acc[mi][ni][r] + gbv, 0.f) + crow[ni * 16];
                crow[ni * 16] = (v - meanv) * invv + betav;
            }
        }
    }
}

// ---------------- skip GEMM (64x128): skipT = relu(Wcat @ g12 + sbcat) ------
__global__ __launch_bounds__(256) void skip_mfma(const short* __restrict__ g12,
                                                 const short* __restrict__ wcat,
                                                 const float* __restrict__ sbcat,
                                                 short* __restrict__ skipT) {
    __shared__ __align__(16) short As[64 * 64];
    __shared__ __align__(16) short Bs[128 * 64];
    int tid = threadIdx.x;
    int s0 = blockIdx.x * 128;
    int m0 = blockIdx.y * 64;
    int b = blockIdx.z;
    f32x4 acc[2][4] = {};
    mfma_tile<256>(g12 + (((size_t)((b << 10) + m0)) << 8), 256,
                   wcat + ((size_t)s0 << 8), 256, As, Bs, tid, acc);
    int wave = tid >> 6, lane = tid & 63;
    int wm = (wave & 1) * 32, wn = (wave >> 1) * 64;
    int quad = lane >> 4, lrow = lane & 15;
#pragma unroll
    for (int mi = 0; mi < 2; ++mi) {
#pragma unroll
        for (int r = 0; r < 4; ++r) {
            int m = m0 + wm + mi * 16 + quad * 4 + r;
            short* crow = skipT + (((size_t)((b << 10) + m)) << 8) + s0 + wn + lrow;
#pragma unroll
            for (int ni = 0; ni < 4; ++ni) {
                int col = s0 + wn + lrow + ni * 16;
                crow[ni * 16] = f2bf(fmaxf(acc[mi][ni][r] + sbcat[col], 0.f));
            }
        }
    }
}

// ---------------- end1 (64x128): y1 = relu(e1w @ skipT + e1b) ----------------
__global__ __launch_bounds__(256) void end1_mfma(const short* __restrict__ skipT,
                                                 const short* __restrict__ e1wb,
                                                 const float* __restrict__ e1b,
                                                 short* __restrict__ y1) {
    __shared__ __align__(16) short As[64 * 64];
    __shared__ __align__(16) short Bs[128 * 64];
    int tid = threadIdx.x;
    int n0 = blockIdx.x * 128;
    int e0 = blockIdx.y * 64;
    int b = blockIdx.z;
    f32x4 acc[2][4] = {};
    mfma_tile<256>(e1wb + ((size_t)e0 << 8), 256,
                   skipT + (((size_t)((b << 10) + n0)) << 8), 256, As, Bs, tid, acc);
    int wave = tid >> 6, lane = tid & 63;
    int wm = (wave & 1) * 32, wn = (wave >> 1) * 64;
    int quad = lane >> 4, lrow = lane & 15;
#pragma unroll
    for (int mi = 0; mi < 2; ++mi) {
#pragma unroll
        for (int r = 0; r < 4; ++r) {
            int e = e0 + wm + mi * 16 + quad * 4 + r;
            float bv = e1b[e];
            short* crow = y1 + (((size_t)(b * 512 + e)) << 10) + n0 + wn + lrow;
#pragma unroll
            for (int ni = 0; ni < 4; ++ni)
                crow[ni * 16] = f2bf(fmaxf(acc[mi][ni][r] + bv, 0.f));
        }
    }
}

// ---------------- end2: out[b,n,o] = W2 @ y1 + b2 (parallel e-split) --------
__global__ __launch_bounds__(256) void end2_kernel(const short* __restrict__ y1,
                                                   const float* __restrict__ w2,
                                                   const float* __restrict__ b2,
                                                   float* __restrict__ out) {
    __shared__ float sw[12][512];
    __shared__ float ps[4][12][128];
    int tid = threadIdx.x;
    for (int idx = tid; idx < 6144; idx += 256) sw[idx >> 9][idx & 511] = w2[idx];
    __syncthreads();
    int n0 = blockIdx.x * 128;
    int bb = blockIdx.y;
    int nl = (tid & 63) * 2;
    int ec = tid >> 6;
    float acc0[12], acc1[12];
#pragma unroll
    for (int o = 0; o < 12; ++o) { acc0[o] = 0.f; acc1[o] = 0.f; }
    const short* yb = y1 + (((size_t)(bb * 512 + ec * 128)) << 10) + n0 + nl;
    for (int e = 0; e < 128; ++e) {
        ushort2 yv = *(const ushort2*)(yb + ((size_t)e << 10));
        float v0 = bf2f((short)yv.x), v1 = bf2f((short)yv.y);
        const float* we = &sw[0][ec * 128 + e];
#pragma unroll
        for (int o = 0; o < 12; ++o) {
            float wv = we[o * 512];
            acc0[o] += wv * v0;
            acc1[o] += wv * v1;
        }
    }
#pragma unroll
    for (int o = 0; o < 12; ++o) {
        ps[ec][o][nl] = acc0[o];
        ps[ec][o][nl + 1] = acc1[o];
    }
    __syncthreads();
    for (int idx = tid; idx < 1536; idx += 256) {
        int o = idx >> 7, nn = idx & 127;
        float s = b2[o] + ps[0][o][nn] + ps[1][o][nn] + ps[2][o][nn] + ps[3][o][nn];
        out[((size_t)(bb * NNODE + nn + n0)) * 12 + o] = s;
    }
}

extern "C" void kernel_launch(void* const* d_in, const int* in_sizes, int n_in,
                              void* d_out, int out_size, void* d_ws, size_t ws_size,
                              hipStream_t stream) {
    const float* x       = (const float*)d_in[0];
    const float* emb     = (const float*)d_in[1];
    const float* start_w = (const float*)d_in[2];
    const float* start_b = (const float*)d_in[3];
    const float* tcn_w   = (const float*)d_in[4];
    const float* tcn_b   = (const float*)d_in[5];
    const float* skip_w  = (const float*)d_in[6];
    const float* skip_b  = (const float*)d_in[7];
    const float* gcn_w   = (const float*)d_in[8];
    const float* gcn_b   = (const float*)d_in[9];
    const float* bn_g    = (const float*)d_in[10];
    const float* bn_b    = (const float*)d_in[11];
    const float* bn_m    = (const float*)d_in[12];
    const float* bn_v    = (const float*)d_in[13];
    const float* e1w     = (const float*)d_in[14];
    const float* e1b     = (const float*)d_in[15];
    const float* e2w     = (const float*)d_in[16];
    const float* e2b     = (const float*)d_in[17];
    float* out = (float*)d_out;

    char* wsb = (char*)d_ws;
    short* adpT  = (short*)(wsb);                    // 2,097,152
    float* mx    = (float*)(wsb + 2097152u);         // 4,096
    float* inv   = (float*)(wsb + 2101248u);         // 4,096
    float* h     = (float*)(wsb + 2105344u);         // 27,262,976
    short* gm    = (short*)(wsb + 29368320u);        // 12,582,912 (max Lt=12)
    short* g12   = (short*)(wsb + 41951232u);        // 8,388,608
    short* wcat  = (short*)(wsb + 50339840u);        // 131,072
    float* sbcat = (float*)(wsb + 50470912u);        // 1,024
    short* e1wb  = (short*)(wsb + 50471936u);        // 262,144
    short* skipT = (short*)(wsb + 50734080u);        // 8,388,608
    short* y1    = (short*)(wsb + 59122688u);        // 16,777,216

    prep_kernel<<<dim3(2624), dim3(256), 0, stream>>>(
        emb, x, start_w, start_b, skip_w, skip_b, e1w,
        mx, inv, h, wcat, sbcat, e1wb);
    adpT_kernel<<<dim3(1024), dim3(256), 0, stream>>>(emb, mx, inv, adpT);

    const int dil[8] = {1, 2, 1, 2, 1, 2, 1, 2};
    const int t0s[8] = {1, 3, 4, 6, 7, 9, 10, 12};
    for (int i = 0; i < 8; ++i) {
        int d = dil[i];
        int t0 = t0s[i];
        int Lt = 13 - t0;
        tcn_mfma<<<dim3(8, Lt, 16), dim3(256), 0, stream>>>(
            h, gm, g12, tcn_w + i * 2048, tcn_b + i * 32, gcn_w + i * 1024,
            d, t0, Lt, i);
        diff_fused<<<dim3(8, 8 * Lt), dim3(256), 0, stream>>>(
            gm, adpT, h, gcn_b + i * 32,
            bn_g + i * 32, bn_b + i * 32, bn_m + i * 32, bn_v + i * 32, t0, Lt);
    }

    skip_mfma<<<dim3(2, 16, 16), dim3(256), 0, stream>>>(g12, wcat, sbcat, skipT);
    end1_mfma<<<dim3(8, 8, 16), dim3(256), 0, stream>>>(skipT, e1wb, e1b, y1);
    end2_kernel<<<dim3(8, 16), dim3(256), 0, stream>>>(y1, e2w, e2b, out);
}